// Round 10
// baseline (984.718 us; speedup 1.0000x reference)
//
#include <hip/hip_runtime.h>

// Problem constants
#define N_NODESC 50000
#define N_EDGESC 800000
#define EPSF 1e-5f
#define NTILE 782                   // ceil(50000/64)
#define NKEYS 800768                // 3128*256 = NTILE*4*256 (full tile range)
#define NHBLK 3128
#define NEBLK 3125                  // 800000/256

typedef __attribute__((ext_vector_type(8))) short short8;
typedef __attribute__((ext_vector_type(16))) float f32x16;

// ---- ws layout (bytes), total ~51.9 MB ----
#define WS_SCALE 0
#define WS_SHIFT 256
#define WS_BSUM  512                  // 3128 int
#define WS_PBUF  13056                // 782*128 f32
#define WS_HIST  413440               // 800768 int
#define WS_FILL  3616512              // 800768 int (contiguous after hist)
#define WS_SEG   6819584              // 800769 int
#define WS_ELIST 10022720             // 800000 int (src only)
#define WS_AHI   13222720             // 128 KB
#define WS_ALO   13353792             // 128 KB
#define WS_HHI   13484864             // 50000*64 ushort
#define WS_HLO   19884864
#define WS_HB    26284864             // 50000*64 f32
#define WS_OUTB  39084864

// key = (tile64, dlq, combo, dl) ; (d>>4) = tile*4 + dlq
__device__ __forceinline__ int edge_key(int d, int c) {
    return (d >> 4) * 256 + c * 16 + (d & 15);
}

// ---------------- histogram ----------------
__global__ __launch_bounds__(256)
void k_hist(const int* __restrict__ src, const int* __restrict__ dst,
            const int* __restrict__ labels, const int* __restrict__ bidx,
            int* __restrict__ hist)
{
    const int e = blockIdx.x * 256 + threadIdx.x;
    if (e >= N_EDGESC) return;
    const int s = src[e], d = dst[e];
    const int c = (labels[d] * 2 + labels[s]) * 4 + bidx[e];
    atomicAdd(&hist[edge_key(d, c)], 1);
}

// ---------------- 3-level scan ----------------
__global__ __launch_bounds__(256)
void k_bsum(const int* __restrict__ hist, int* __restrict__ bsum)
{
    __shared__ int s[256];
    const int i = blockIdx.x * 256 + threadIdx.x;
    s[threadIdx.x] = hist[i];
    __syncthreads();
    for (int off = 128; off > 0; off >>= 1) {
        if (threadIdx.x < off) s[threadIdx.x] += s[threadIdx.x + off];
        __syncthreads();
    }
    if (threadIdx.x == 0) bsum[blockIdx.x] = s[0];
}

__global__ __launch_bounds__(1024)
void k_bscan2(int* __restrict__ bsum)   // in-place exclusive scan of NHBLK entries
{
    __shared__ int s[1024];
    const int t = threadIdx.x;
    int v[4]; int tot = 0;
#pragma unroll
    for (int j = 0; j < 4; ++j) {
        const int i = t * 4 + j;
        v[j] = (i < NHBLK) ? bsum[i] : 0;
        tot += v[j];
    }
    s[t] = tot; __syncthreads();
    for (int off = 1; off < 1024; off <<= 1) {
        const int x = (t >= off) ? s[t - off] : 0;
        __syncthreads();
        s[t] += x;
        __syncthreads();
    }
    int base = s[t] - tot;
#pragma unroll
    for (int j = 0; j < 4; ++j) {
        const int i = t * 4 + j;
        if (i < NHBLK) bsum[i] = base;
        base += v[j];
    }
}

__global__ __launch_bounds__(256)
void k_escan2(const int* __restrict__ hist, const int* __restrict__ bsum,
              int* __restrict__ seg)
{
    __shared__ int s[256];
    const int t = threadIdx.x;
    const int i = blockIdx.x * 256 + t;
    const int v = hist[i];
    s[t] = v; __syncthreads();
    for (int off = 1; off < 256; off <<= 1) {
        const int x = (t >= off) ? s[t - off] : 0;
        __syncthreads();
        s[t] += x;
        __syncthreads();
    }
    const int incl = s[t];
    seg[i] = bsum[blockIdx.x] + incl - v;
    if (i == NKEYS - 1) seg[NKEYS] = bsum[blockIdx.x] + incl;
}

__global__ __launch_bounds__(256)
void k_scat(const int* __restrict__ src, const int* __restrict__ dst,
            const int* __restrict__ labels, const int* __restrict__ bidx,
            const int* __restrict__ seg, int* __restrict__ fill,
            int* __restrict__ elist)
{
    const int e = blockIdx.x * 256 + threadIdx.x;
    if (e >= N_EDGESC) return;
    const int s = src[e], d = dst[e];
    const int c = (labels[d] * 2 + labels[s]) * 4 + bidx[e];
    const int k = edge_key(d, c);
    const int pos = seg[k] + atomicAdd(&fill[k], 1);
    elist[pos] = s;
}

// ---- MFMA A-fragments (split bf16 hi/lo), layout verified R5 ----
__global__ void k_mfrag(const float* __restrict__ M, ushort* __restrict__ Ahi,
                        ushort* __restrict__ Alo)
{
    const int c = blockIdx.x;
    for (int slot = threadIdx.x; slot < 512; slot += 256) {
        const int t = slot >> 8, s = (slot >> 6) & 3, lane = slot & 63;
        const int row = (lane & 31) + 32 * t;
        const int kb = 16 * s + 8 * (lane >> 5);
        const int fid = ((c * 2 + t) * 4 + s) * 64 + lane;
#pragma unroll
        for (int j = 0; j < 8; ++j) {
            const float v = M[c * 4096 + row * 64 + kb + j];
            const unsigned b = __float_as_uint(v);
            const float lof = v - __uint_as_float(b & 0xFFFF0000u);
            Ahi[fid * 8 + j] = (ushort)(b >> 16);
            Alo[fid * 8 + j] = (ushort)(__float_as_uint(lof) >> 16);
        }
    }
}

// ---------------- h = in @ W + b, + split-bf16 outputs ----------------
__global__ __launch_bounds__(256)
void k_h(const float* __restrict__ in, const float* __restrict__ W,
         const float* __restrict__ b, float* __restrict__ h,
         ushort* __restrict__ hhi, ushort* __restrict__ hlo, const int F)
{
    const int t = blockIdx.x * 256 + threadIdx.x;
    if (t >= N_NODESC * 64) return;
    const int n = t >> 6, e = t & 63;
    const float* __restrict__ xr = in + (long)n * F;
    float acc = b[e];
    for (int f = 0; f < F; f += 4) {
        acc += xr[f]     * W[f * 64 + e];
        acc += xr[f + 1] * W[(f + 1) * 64 + e];
        acc += xr[f + 2] * W[(f + 2) * 64 + e];
        acc += xr[f + 3] * W[(f + 3) * 64 + e];
    }
    h[t] = acc;
    const unsigned bb = __float_as_uint(acc);
    const float lof = acc - __uint_as_float(bb & 0xFFFF0000u);
    hhi[t] = (ushort)(bb >> 16);
    hlo[t] = (ushort)(__float_as_uint(lof) >> 16);
}

// ---------------- fused LN-apply + relu + next-layer GEMM + split -----------
__global__ __launch_bounds__(256)
void k_happly(const float* __restrict__ outb, const float* __restrict__ scale,
              const float* __restrict__ shift, const float* __restrict__ W,
              const float* __restrict__ b, float* __restrict__ h,
              ushort* __restrict__ hhi, ushort* __restrict__ hlo)
{
    __shared__ float act[4][64];
    const int nl = threadIdx.x >> 6, o = threadIdx.x & 63;
    const int n = blockIdx.x * 4 + nl;
    const float v = outb[(long)n * 64 + o] * scale[o] + shift[o];
    act[nl][o] = fmaxf(v, 0.f);
    __syncthreads();
    float a = b[o];
#pragma unroll 16
    for (int f = 0; f < 64; ++f) a += act[nl][f] * W[f * 64 + o];
    const long t = (long)n * 64 + o;
    h[t] = a;
    const unsigned bb = __float_as_uint(a);
    const float lof = a - __uint_as_float(bb & 0xFFFF0000u);
    hhi[t] = (ushort)(bb >> 16);
    hlo[t] = (ushort)(__float_as_uint(lof) >> 16);
}

// ---------------- MFMA transform + register aggregation (R8 structure +
// cross-combo software pipeline: elist prefetched 2 combos ahead, B-fragment
// gathers issued 1 combo ahead into a second register set) ------------------
__global__ __launch_bounds__(256, 3)
void k_msgF(const ushort* __restrict__ hhi, const ushort* __restrict__ hlo,
            const float* __restrict__ hres, const int* __restrict__ elist,
            const int* __restrict__ seg, const ushort* __restrict__ Ahi,
            const ushort* __restrict__ Alo, float* __restrict__ outb,
            float* __restrict__ pbuf)
{
    __shared__ float msg[4][2048];        // per-wave 32 edges x 64 feats (32 KB)
    __shared__ float red[2][4][64];
    const int tid = threadIdx.x;
    const int w = tid >> 6, lane = tid & 63;
    const int col = lane & 31, hig = lane >> 5;     // MFMA roles
    const int dl = lane >> 2, fq = lane & 3;        // reduce roles
    const int tile = blockIdx.x;
    const int kbase = (tile * 4 + w) * 256;
    float* __restrict__ msgw = msg[w];

    float4 a0 = {0,0,0,0}, a1 = a0, a2 = a0, a3 = a0;

    // ---- pipeline state: S0=S_c, S1=S_{c+1}, S1n=S_{c+2} ----
    int S0  = seg[kbase];
    int S1  = seg[kbase + 16];
    int S1n = seg[kbase + 32];

    short8 bhA[4], blA[4], bhB[4], blB[4];
    {   // B-frags for combo 0, chunk 0
        const int ep0 = (S0 < S1) ? elist[min(S0 + col, S1 - 1)] : 0;
        const ushort* __restrict__ rh = hhi + ep0 * 64 + hig * 8;
        const ushort* __restrict__ rl = hlo + ep0 * 64 + hig * 8;
#pragma unroll
        for (int s = 0; s < 4; ++s) {
            bhA[s] = *(const short8*)&rh[s * 16];
            blA[s] = *(const short8*)&rl[s * 16];
        }
    }
    // elist for combo 1, chunk 0 (in flight)
    int epN = (S1 < S1n) ? elist[min(S1 + col, S1n - 1)] : 0;

    for (int c = 0; c < 16; ++c) {
        // ---- issue B-frags for combo c+1 chunk 0 (epN arrived ~1 combo ago) ----
        {
            const ushort* __restrict__ rh = hhi + epN * 64 + hig * 8;
            const ushort* __restrict__ rl = hlo + epN * 64 + hig * 8;
#pragma unroll
            for (int s = 0; s < 4; ++s) {
                bhB[s] = *(const short8*)&rh[s * 16];
                blB[s] = *(const short8*)&rl[s * 16];
            }
        }
        // ---- prefetch elist for combo c+2 ----
        const int S1nn = seg[kbase + min(c + 3, 16) * 16];
        const int epNN = (c < 14 && S1n < S1nn) ? elist[min(S1n + col, S1nn - 1)] : 0;

        if (S0 < S1) {
            const int rlo = seg[kbase + c * 16 + dl];
            const int rhi = seg[kbase + c * 16 + dl + 1];
            bool first = true;
            for (int p = S0; p < S1; p += 32) {
                if (!first) {   // rare multi-chunk tail: serial reload into A-set
                    const int ep2 = elist[min(p + col, S1 - 1)];
                    const ushort* __restrict__ rh = hhi + ep2 * 64 + hig * 8;
                    const ushort* __restrict__ rl = hlo + ep2 * 64 + hig * 8;
#pragma unroll
                    for (int s = 0; s < 4; ++s) {
                        bhA[s] = *(const short8*)&rh[s * 16];
                        blA[s] = *(const short8*)&rl[s * 16];
                    }
                }
                first = false;

                f32x16 c0, c1;
#pragma unroll
                for (int i = 0; i < 16; ++i) { c0[i] = 0.f; c1[i] = 0.f; }
#pragma unroll
                for (int s = 0; s < 4; ++s) {
                    const int fidb = (c * 8 + s) * 64 + lane;
                    const short8 a0h = *(const short8*)&Ahi[fidb * 8];
                    const short8 a1h = *(const short8*)&Ahi[(fidb + 256) * 8];
                    const short8 a0l = *(const short8*)&Alo[fidb * 8];
                    const short8 a1l = *(const short8*)&Alo[(fidb + 256) * 8];
                    c0 = __builtin_amdgcn_mfma_f32_32x32x16_bf16(a0h, bhA[s], c0, 0, 0, 0);
                    c1 = __builtin_amdgcn_mfma_f32_32x32x16_bf16(a1h, bhA[s], c1, 0, 0, 0);
                    c0 = __builtin_amdgcn_mfma_f32_32x32x16_bf16(a0h, blA[s], c0, 0, 0, 0);
                    c1 = __builtin_amdgcn_mfma_f32_32x32x16_bf16(a1h, blA[s], c1, 0, 0, 0);
                    c0 = __builtin_amdgcn_mfma_f32_32x32x16_bf16(a0l, bhA[s], c0, 0, 0, 0);
                    c1 = __builtin_amdgcn_mfma_f32_32x32x16_bf16(a1l, bhA[s], c1, 0, 0, 0);
                }

                // stage message tile: msg[col][feat], feat XOR-swizzled
                const int sw = (col & 7) << 3;
                const int cb = col * 64;
#pragma unroll
                for (int rq = 0; rq < 4; ++rq) {
                    const int fb = 8 * rq + 4 * hig;   // C row = (r&3)+8(r>>2)+4hig
                    float4 v0 = {c0[4*rq], c0[4*rq+1], c0[4*rq+2], c0[4*rq+3]};
                    float4 v1 = {c1[4*rq], c1[4*rq+1], c1[4*rq+2], c1[4*rq+3]};
                    *(float4*)&msgw[cb + (fb ^ sw)] = v0;
                    *(float4*)&msgw[cb + ((fb + 32) ^ sw)] = v1;
                }
                asm volatile("s_waitcnt lgkmcnt(0)" ::: "memory");

                // wave-local segmented sum: lane (dl,fq) sums its dl's rows
                const int lo = max(rlo - p, 0);
                const int hi = min(rhi - p, 32);
                for (int q = lo; q < hi; ++q) {
                    const int qs = (q & 7) << 3;
                    const int qb = q * 64;
                    const float4 v0 = *(const float4*)&msgw[qb + ((16*fq + 0) ^ qs)];
                    const float4 v1 = *(const float4*)&msgw[qb + ((16*fq + 4) ^ qs)];
                    const float4 v2 = *(const float4*)&msgw[qb + ((16*fq + 8) ^ qs)];
                    const float4 v3 = *(const float4*)&msgw[qb + ((16*fq + 12) ^ qs)];
                    a0.x += v0.x; a0.y += v0.y; a0.z += v0.z; a0.w += v0.w;
                    a1.x += v1.x; a1.y += v1.y; a1.z += v1.z; a1.w += v1.w;
                    a2.x += v2.x; a2.y += v2.y; a2.z += v2.z; a2.w += v2.w;
                    a3.x += v3.x; a3.y += v3.y; a3.z += v3.z; a3.w += v3.w;
                }
                asm volatile("s_waitcnt lgkmcnt(0)" ::: "memory");
            }
        }

        // ---- rotate pipeline state ----
#pragma unroll
        for (int s = 0; s < 4; ++s) { bhA[s] = bhB[s]; blA[s] = blB[s]; }
        epN = epNN;
        S0 = S1; S1 = S1n; S1n = S1nn;
    }

    // ---- epilogue: residual + store + LN partials (shfl over dl lanes) ----
    const int gd = tile * 64 + w * 16 + dl;
    float4 v[4] = {a0, a1, a2, a3};
    if (gd < N_NODESC) {
        const float4* __restrict__ hr = (const float4*)(hres + (long)gd * 64 + 16 * fq);
        float4* __restrict__ ob = (float4*)(outb + (long)gd * 64 + 16 * fq);
#pragma unroll
        for (int u = 0; u < 4; ++u) {
            const float4 r = hr[u];
            v[u].x += r.x; v[u].y += r.y; v[u].z += r.z; v[u].w += r.w;
            ob[u] = v[u];
        }
    } else {
#pragma unroll
        for (int u = 0; u < 4; ++u) v[u] = make_float4(0.f, 0.f, 0.f, 0.f);
    }
    float s1[16], s2[16];
#pragma unroll
    for (int u = 0; u < 4; ++u) {
        s1[4*u+0] = v[u].x; s2[4*u+0] = v[u].x * v[u].x;
        s1[4*u+1] = v[u].y; s2[4*u+1] = v[u].y * v[u].y;
        s1[4*u+2] = v[u].z; s2[4*u+2] = v[u].z * v[u].z;
        s1[4*u+3] = v[u].w; s2[4*u+3] = v[u].w * v[u].w;
    }
#pragma unroll
    for (int j = 0; j < 16; ++j) {
        s1[j] += __shfl_xor(s1[j], 4);  s2[j] += __shfl_xor(s2[j], 4);
        s1[j] += __shfl_xor(s1[j], 8);  s2[j] += __shfl_xor(s2[j], 8);
        s1[j] += __shfl_xor(s1[j], 16); s2[j] += __shfl_xor(s2[j], 16);
        s1[j] += __shfl_xor(s1[j], 32); s2[j] += __shfl_xor(s2[j], 32);
    }
    if (dl == 0) {
#pragma unroll
        for (int j = 0; j < 16; ++j) {
            red[0][w][16 * fq + j] = s1[j];
            red[1][w][16 * fq + j] = s2[j];
        }
    }
    __syncthreads();
    if (tid < 64) {
        const float t1 = red[0][0][tid] + red[0][1][tid] + red[0][2][tid] + red[0][3][tid];
        const float t2 = red[1][0][tid] + red[1][1][tid] + red[1][2][tid] + red[1][3][tid];
        pbuf[tile * 128 + tid] = t1;
        pbuf[tile * 128 + 64 + tid] = t2;
    }
}

// ---------------- reduce LN partials -> scale/shift ----------------
__global__ __launch_bounds__(1024)
void k_norm2(const float* __restrict__ pbuf, const float* __restrict__ g,
             const float* __restrict__ be, float* __restrict__ scale,
             float* __restrict__ shift)
{
    __shared__ float s[1024];
    const int t = threadIdx.x, j = t & 127, gg = t >> 7;
    float a = 0.f;
    for (int b = gg; b < NTILE; b += 8) a += pbuf[b * 128 + j];
    s[t] = a;
    __syncthreads();
    if (t < 128) {
        float tot = 0.f;
#pragma unroll
        for (int k = 0; k < 8; ++k) tot += s[j + 128 * k];
        s[t] = tot;
    }
    __syncthreads();
    if (t < 64) {
        const double mu  = (double)s[t] / (double)N_NODESC;
        const double var = (double)s[64 + t] / (double)N_NODESC - mu * mu;
        const double sc  = (double)g[t] / sqrt(var + (double)EPSF);
        scale[t] = (float)sc;
        shift[t] = (float)((double)be[t] - mu * sc);
    }
}

// ---------------- final projection (LN apply fused) ----------------
__global__ __launch_bounds__(256)
void k_out(const float* __restrict__ outb, const float* __restrict__ scale,
           const float* __restrict__ shift, const float* __restrict__ resW,
           const float* __restrict__ resb, float* __restrict__ out)
{
    const int n = blockIdx.x * 256 + threadIdx.x;
    if (n >= N_NODESC) return;
    float a0 = resb[0], a1 = resb[1];
    const float* __restrict__ r = outb + (long)n * 64;
#pragma unroll 8
    for (int e = 0; e < 64; ++e) {
        const float v = fmaxf(r[e] * scale[e] + shift[e], 0.f);
        a0 += v * resW[2 * e];
        a1 += v * resW[2 * e + 1];
    }
    out[2 * n] = a0;
    out[2 * n + 1] = a1;
}

extern "C" void kernel_launch(void* const* d_in, const int* in_sizes, int n_in,
                              void* d_out, int out_size, void* d_ws, size_t ws_size,
                              hipStream_t stream)
{
    const float* x      = (const float*)d_in[0];
    const float* M      = (const float*)d_in[1];
    const int*   src    = (const int*)d_in[2];
    const int*   dst    = (const int*)d_in[3];
    const int*   labels = (const int*)d_in[4];
    const int*   bidx   = (const int*)d_in[5];
    const float* resW   = (const float*)d_in[18];
    const float* resb   = (const float*)d_in[19];
    float* out = (float*)d_out;

    char* ws = (char*)d_ws;
    float*  scale = (float*)(ws + WS_SCALE);
    float*  shift = (float*)(ws + WS_SHIFT);
    int*    bsum  = (int*)(ws + WS_BSUM);
    float*  pbuf  = (float*)(ws + WS_PBUF);
    int*    hist  = (int*)(ws + WS_HIST);
    int*    fill  = (int*)(ws + WS_FILL);
    int*    seg   = (int*)(ws + WS_SEG);
    int*    elist = (int*)(ws + WS_ELIST);
    ushort* Ahi   = (ushort*)(ws + WS_AHI);
    ushort* Alo   = (ushort*)(ws + WS_ALO);
    ushort* hhi   = (ushort*)(ws + WS_HHI);
    ushort* hlo   = (ushort*)(ws + WS_HLO);
    float*  hB    = (float*)(ws + WS_HB);
    float*  outb  = (float*)(ws + WS_OUTB);

    const int NB64 = (N_NODESC * 64 + 255) / 256;  // 12500

    // ---- preprocessing (graph + M constant across layers) ----
    hipMemsetAsync(hist, 0, 2 * (size_t)NKEYS * sizeof(int), stream);  // hist + fill
    k_hist<<<NEBLK, 256, 0, stream>>>(src, dst, labels, bidx, hist);
    k_bsum<<<NHBLK, 256, 0, stream>>>(hist, bsum);
    k_bscan2<<<1, 1024, 0, stream>>>(bsum);
    k_escan2<<<NHBLK, 256, 0, stream>>>(hist, bsum, seg);
    k_scat<<<NEBLK, 256, 0, stream>>>(src, dst, labels, bidx, seg, fill, elist);
    k_mfrag<<<16, 256, 0, stream>>>(M, Ahi, Alo);

    for (int l = 0; l < 3; ++l) {
        const float* W  = (const float*)d_in[6 + 4 * l];
        const float* b  = (const float*)d_in[7 + 4 * l];
        const float* g  = (const float*)d_in[8 + 4 * l];
        const float* be = (const float*)d_in[9 + 4 * l];

        if (l == 0) {
            k_h<<<NB64, 256, 0, stream>>>(x, W, b, hB, hhi, hlo, 128);
        } else {
            k_happly<<<N_NODESC / 4, 256, 0, stream>>>(outb, scale, shift, W, b,
                                                       hB, hhi, hlo);
        }
        k_msgF<<<NTILE, 256, 0, stream>>>(hhi, hlo, hB, elist, seg, Ahi, Alo,
                                          outb, pbuf);
        k_norm2<<<1, 1024, 0, stream>>>(pbuf, g, be, scale, shift);
    }
    k_out<<<(N_NODESC + 255) / 256, 256, 0, stream>>>(outb, scale, shift, resW, resb, out);
    (void)in_sizes; (void)n_in; (void)out_size; (void)ws_size;
}

// Round 11
// 746.742 us; speedup vs baseline: 1.3187x; 1.3187x over previous
//
#include <hip/hip_runtime.h>

// Problem constants
#define N_NODESC 50000
#define N_EDGESC 800000
#define EPSF 1e-5f
#define NTILE 782                   // ceil(50000/64)
#define NQRT  3128                  // NTILE*4 dst-quarters
#define SPLIT 4                     // combo groups per quarter
#define NKEYS 800768                // 3128*256 = NTILE*4*256 (full tile range)
#define NHBLK 3128
#define NEBLK 3125                  // 800000/256

typedef __attribute__((ext_vector_type(8))) short short8;
typedef __attribute__((ext_vector_type(16))) float f32x16;

// ---- ws layout (bytes), total ~103 MB ----
#define WS_SCALE 0
#define WS_SHIFT 256
#define WS_BSUM  512                  // 3128 int
#define WS_PBUF  13056                // 782*128 f32
#define WS_HIST  413440               // 800768 int
#define WS_FILL  3616512              // 800768 int (contiguous after hist)
#define WS_SEG   6819584              // 800769 int
#define WS_ELIST 10022720             // 800000 int (src only)
#define WS_AHI   13222720             // 128 KB
#define WS_ALO   13353792             // 128 KB
#define WS_HHI   13484864             // 50000*64 ushort
#define WS_HLO   19884864
#define WS_HB    26284864             // 50000*64 f32
#define WS_OUTB  39084864
#define WS_PACC  51884864             // NQRT*SPLIT*1024 f32 = 51.25 MB

// key = (tile64, dlq, combo, dl) ; (d>>4) = tile*4 + dlq
__device__ __forceinline__ int edge_key(int d, int c) {
    return (d >> 4) * 256 + c * 16 + (d & 15);
}

// ---------------- histogram ----------------
__global__ __launch_bounds__(256)
void k_hist(const int* __restrict__ src, const int* __restrict__ dst,
            const int* __restrict__ labels, const int* __restrict__ bidx,
            int* __restrict__ hist)
{
    const int e = blockIdx.x * 256 + threadIdx.x;
    if (e >= N_EDGESC) return;
    const int s = src[e], d = dst[e];
    const int c = (labels[d] * 2 + labels[s]) * 4 + bidx[e];
    atomicAdd(&hist[edge_key(d, c)], 1);
}

// ---------------- 3-level scan ----------------
__global__ __launch_bounds__(256)
void k_bsum(const int* __restrict__ hist, int* __restrict__ bsum)
{
    __shared__ int s[256];
    const int i = blockIdx.x * 256 + threadIdx.x;
    s[threadIdx.x] = hist[i];
    __syncthreads();
    for (int off = 128; off > 0; off >>= 1) {
        if (threadIdx.x < off) s[threadIdx.x] += s[threadIdx.x + off];
        __syncthreads();
    }
    if (threadIdx.x == 0) bsum[blockIdx.x] = s[0];
}

__global__ __launch_bounds__(1024)
void k_bscan2(int* __restrict__ bsum)   // in-place exclusive scan of NHBLK entries
{
    __shared__ int s[1024];
    const int t = threadIdx.x;
    int v[4]; int tot = 0;
#pragma unroll
    for (int j = 0; j < 4; ++j) {
        const int i = t * 4 + j;
        v[j] = (i < NHBLK) ? bsum[i] : 0;
        tot += v[j];
    }
    s[t] = tot; __syncthreads();
    for (int off = 1; off < 1024; off <<= 1) {
        const int x = (t >= off) ? s[t - off] : 0;
        __syncthreads();
        s[t] += x;
        __syncthreads();
    }
    int base = s[t] - tot;
#pragma unroll
    for (int j = 0; j < 4; ++j) {
        const int i = t * 4 + j;
        if (i < NHBLK) bsum[i] = base;
        base += v[j];
    }
}

__global__ __launch_bounds__(256)
void k_escan2(const int* __restrict__ hist, const int* __restrict__ bsum,
              int* __restrict__ seg)
{
    __shared__ int s[256];
    const int t = threadIdx.x;
    const int i = blockIdx.x * 256 + t;
    const int v = hist[i];
    s[t] = v; __syncthreads();
    for (int off = 1; off < 256; off <<= 1) {
        const int x = (t >= off) ? s[t - off] : 0;
        __syncthreads();
        s[t] += x;
        __syncthreads();
    }
    const int incl = s[t];
    seg[i] = bsum[blockIdx.x] + incl - v;
    if (i == NKEYS - 1) seg[NKEYS] = bsum[blockIdx.x] + incl;
}

__global__ __launch_bounds__(256)
void k_scat(const int* __restrict__ src, const int* __restrict__ dst,
            const int* __restrict__ labels, const int* __restrict__ bidx,
            const int* __restrict__ seg, int* __restrict__ fill,
            int* __restrict__ elist)
{
    const int e = blockIdx.x * 256 + threadIdx.x;
    if (e >= N_EDGESC) return;
    const int s = src[e], d = dst[e];
    const int c = (labels[d] * 2 + labels[s]) * 4 + bidx[e];
    const int k = edge_key(d, c);
    const int pos = seg[k] + atomicAdd(&fill[k], 1);
    elist[pos] = s;
}

// ---- MFMA A-fragments (split bf16 hi/lo), layout verified R5 ----
__global__ void k_mfrag(const float* __restrict__ M, ushort* __restrict__ Ahi,
                        ushort* __restrict__ Alo)
{
    const int c = blockIdx.x;
    for (int slot = threadIdx.x; slot < 512; slot += 256) {
        const int t = slot >> 8, s = (slot >> 6) & 3, lane = slot & 63;
        const int row = (lane & 31) + 32 * t;
        const int kb = 16 * s + 8 * (lane >> 5);
        const int fid = ((c * 2 + t) * 4 + s) * 64 + lane;
#pragma unroll
        for (int j = 0; j < 8; ++j) {
            const float v = M[c * 4096 + row * 64 + kb + j];
            const unsigned b = __float_as_uint(v);
            const float lof = v - __uint_as_float(b & 0xFFFF0000u);
            Ahi[fid * 8 + j] = (ushort)(b >> 16);
            Alo[fid * 8 + j] = (ushort)(__float_as_uint(lof) >> 16);
        }
    }
}

// ---------------- h = in @ W + b, + split-bf16 outputs ----------------
__global__ __launch_bounds__(256)
void k_h(const float* __restrict__ in, const float* __restrict__ W,
         const float* __restrict__ b, float* __restrict__ h,
         ushort* __restrict__ hhi, ushort* __restrict__ hlo, const int F)
{
    const int t = blockIdx.x * 256 + threadIdx.x;
    if (t >= N_NODESC * 64) return;
    const int n = t >> 6, e = t & 63;
    const float* __restrict__ xr = in + (long)n * F;
    float acc = b[e];
    for (int f = 0; f < F; f += 4) {
        acc += xr[f]     * W[f * 64 + e];
        acc += xr[f + 1] * W[(f + 1) * 64 + e];
        acc += xr[f + 2] * W[(f + 2) * 64 + e];
        acc += xr[f + 3] * W[(f + 3) * 64 + e];
    }
    h[t] = acc;
    const unsigned bb = __float_as_uint(acc);
    const float lof = acc - __uint_as_float(bb & 0xFFFF0000u);
    hhi[t] = (ushort)(bb >> 16);
    hlo[t] = (ushort)(__float_as_uint(lof) >> 16);
}

// ---------------- fused LN-apply + relu + next-layer GEMM + split -----------
__global__ __launch_bounds__(256)
void k_happly(const float* __restrict__ outb, const float* __restrict__ scale,
              const float* __restrict__ shift, const float* __restrict__ W,
              const float* __restrict__ b, float* __restrict__ h,
              ushort* __restrict__ hhi, ushort* __restrict__ hlo)
{
    __shared__ float act[4][64];
    const int nl = threadIdx.x >> 6, o = threadIdx.x & 63;
    const int n = blockIdx.x * 4 + nl;
    const float v = outb[(long)n * 64 + o] * scale[o] + shift[o];
    act[nl][o] = fmaxf(v, 0.f);
    __syncthreads();
    float a = b[o];
#pragma unroll 16
    for (int f = 0; f < 64; ++f) a += act[nl][f] * W[f * 64 + o];
    const long t = (long)n * 64 + o;
    h[t] = a;
    const unsigned bb = __float_as_uint(a);
    const float lof = a - __uint_as_float(bb & 0xFFFF0000u);
    hhi[t] = (ushort)(bb >> 16);
    hlo[t] = (ushort)(__float_as_uint(lof) >> 16);
}

// ---------------- MFMA transform + register aggregation (R8 body, 1-wave
// blocks, combos split 4-ways across blocks; partials to pacc) --------------
// Block = one (dst-quarter, combo-group): quarter gq = bid>>2, hc = bid&3,
// combos hc*4 .. hc*4+3. Per 32-edge chunk: MFMA -> ds_write swizzled msg
// tile -> wave-local segmented sum into registers. No barriers, no atomics.
__global__ __launch_bounds__(64, 4)
void k_msgF(const ushort* __restrict__ hhi, const ushort* __restrict__ hlo,
            const int* __restrict__ elist, const int* __restrict__ seg,
            const ushort* __restrict__ Ahi, const ushort* __restrict__ Alo,
            float* __restrict__ pacc)
{
    __shared__ float msgw[2048];          // 32 edges x 64 feats (8 KB)
    const int lane = threadIdx.x;
    const int col = lane & 31, hig = lane >> 5;     // MFMA roles
    const int dl = lane >> 2, fq = lane & 3;        // reduce roles
    const int gq = blockIdx.x >> 2;       // dst-quarter (tile*4 + dlq)
    const int hc = blockIdx.x & 3;        // combo group
    const int kbase = gq * 256;

    float4 a0 = {0,0,0,0}, a1 = a0, a2 = a0, a3 = a0;

    for (int ci = 0; ci < 4; ++ci) {
        const int c = hc * 4 + ci;
        const int S0 = seg[kbase + c * 16];
        const int S1 = seg[kbase + c * 16 + 16];
        if (S0 >= S1) continue;
        const int rlo = seg[kbase + c * 16 + dl];
        const int rhi = seg[kbase + c * 16 + dl + 1];

        for (int p = S0; p < S1; p += 32) {
            const int idx = p + col;
            const int srcn = elist[(idx < S1) ? idx : (S1 - 1)];

            // B fragments from split tables (pattern verified R5)
            const ushort* __restrict__ rh = hhi + srcn * 64 + hig * 8;
            const ushort* __restrict__ rl = hlo + srcn * 64 + hig * 8;
            short8 bh[4], bl[4];
#pragma unroll
            for (int s = 0; s < 4; ++s) {
                bh[s] = *(const short8*)&rh[s * 16];
                bl[s] = *(const short8*)&rl[s * 16];
            }

            f32x16 c0, c1;
#pragma unroll
            for (int i = 0; i < 16; ++i) { c0[i] = 0.f; c1[i] = 0.f; }
#pragma unroll
            for (int s = 0; s < 4; ++s) {
                const int fidb = (c * 8 + s) * 64 + lane;
                const short8 a0h = *(const short8*)&Ahi[fidb * 8];
                const short8 a1h = *(const short8*)&Ahi[(fidb + 256) * 8];
                const short8 a0l = *(const short8*)&Alo[fidb * 8];
                const short8 a1l = *(const short8*)&Alo[(fidb + 256) * 8];
                c0 = __builtin_amdgcn_mfma_f32_32x32x16_bf16(a0h, bh[s], c0, 0, 0, 0);
                c1 = __builtin_amdgcn_mfma_f32_32x32x16_bf16(a1h, bh[s], c1, 0, 0, 0);
                c0 = __builtin_amdgcn_mfma_f32_32x32x16_bf16(a0h, bl[s], c0, 0, 0, 0);
                c1 = __builtin_amdgcn_mfma_f32_32x32x16_bf16(a1h, bl[s], c1, 0, 0, 0);
                c0 = __builtin_amdgcn_mfma_f32_32x32x16_bf16(a0l, bh[s], c0, 0, 0, 0);
                c1 = __builtin_amdgcn_mfma_f32_32x32x16_bf16(a1l, bh[s], c1, 0, 0, 0);
            }

            // stage message tile: msg[col][feat], feat XOR-swizzled
            const int sw = (col & 7) << 3;
            const int cb = col * 64;
#pragma unroll
            for (int rq = 0; rq < 4; ++rq) {
                const int fb = 8 * rq + 4 * hig;     // C row = (r&3)+8(r>>2)+4hig
                float4 v0 = {c0[4*rq], c0[4*rq+1], c0[4*rq+2], c0[4*rq+3]};
                float4 v1 = {c1[4*rq], c1[4*rq+1], c1[4*rq+2], c1[4*rq+3]};
                *(float4*)&msgw[cb + (fb ^ sw)] = v0;
                *(float4*)&msgw[cb + ((fb + 32) ^ sw)] = v1;
            }
            asm volatile("s_waitcnt lgkmcnt(0)" ::: "memory");

            // wave-local segmented sum: lane (dl,fq) sums its dl's rows
            const int lo = max(rlo - p, 0);
            const int hi = min(rhi - p, 32);
            for (int q = lo; q < hi; ++q) {
                const int qs = (q & 7) << 3;
                const int qb = q * 64;
                const float4 v0 = *(const float4*)&msgw[qb + ((16*fq + 0) ^ qs)];
                const float4 v1 = *(const float4*)&msgw[qb + ((16*fq + 4) ^ qs)];
                const float4 v2 = *(const float4*)&msgw[qb + ((16*fq + 8) ^ qs)];
                const float4 v3 = *(const float4*)&msgw[qb + ((16*fq + 12) ^ qs)];
                a0.x += v0.x; a0.y += v0.y; a0.z += v0.z; a0.w += v0.w;
                a1.x += v1.x; a1.y += v1.y; a1.z += v1.z; a1.w += v1.w;
                a2.x += v2.x; a2.y += v2.y; a2.z += v2.z; a2.w += v2.w;
                a3.x += v3.x; a3.y += v3.y; a3.z += v3.z; a3.w += v3.w;
            }
            asm volatile("s_waitcnt lgkmcnt(0)" ::: "memory");
        }
    }

    // partial output: pacc[bid][dl][feat]
    float* __restrict__ pa = pacc + (long)blockIdx.x * 1024 + dl * 64 + 16 * fq;
    *(float4*)&pa[0]  = a0;
    *(float4*)&pa[4]  = a1;
    *(float4*)&pa[8]  = a2;
    *(float4*)&pa[12] = a3;
}

// ---------------- combine SPLIT partials + residual + LN partials ----------
__global__ __launch_bounds__(256)
void k_comb(const float* __restrict__ pacc, const float* __restrict__ hres,
            float* __restrict__ outb, float* __restrict__ pbuf)
{
    __shared__ float red[2][4][64];
    const int tid = threadIdx.x;
    const int o = tid & 63, r = tid >> 6;
    const int tile = blockIdx.x;
    float s1 = 0.f, s2 = 0.f;
#pragma unroll 4
    for (int i = 0; i < 16; ++i) {
        const int nl = r + 4 * i;              // 0..63
        const int n = tile * 64 + nl;
        if (n < N_NODESC) {
            const long pb = ((long)(tile * 4 + (nl >> 4)) * 4) * 1024 + (nl & 15) * 64 + o;
            float v = hres[(long)n * 64 + o];
            v += pacc[pb] + pacc[pb + 1024] + pacc[pb + 2048] + pacc[pb + 3072];
            outb[(long)n * 64 + o] = v;
            s1 += v; s2 += v * v;
        }
    }
    red[0][r][o] = s1; red[1][r][o] = s2;
    __syncthreads();
    if (tid < 64) {
        pbuf[tile * 128 + tid] = red[0][0][tid] + red[0][1][tid] + red[0][2][tid] + red[0][3][tid];
        pbuf[tile * 128 + 64 + tid] = red[1][0][tid] + red[1][1][tid] + red[1][2][tid] + red[1][3][tid];
    }
}

// ---------------- reduce LN partials -> scale/shift ----------------
__global__ __launch_bounds__(1024)
void k_norm2(const float* __restrict__ pbuf, const float* __restrict__ g,
             const float* __restrict__ be, float* __restrict__ scale,
             float* __restrict__ shift)
{
    __shared__ float s[1024];
    const int t = threadIdx.x, j = t & 127, gg = t >> 7;
    float a = 0.f;
    for (int b = gg; b < NTILE; b += 8) a += pbuf[b * 128 + j];
    s[t] = a;
    __syncthreads();
    if (t < 128) {
        float tot = 0.f;
#pragma unroll
        for (int k = 0; k < 8; ++k) tot += s[j + 128 * k];
        s[t] = tot;
    }
    __syncthreads();
    if (t < 64) {
        const double mu  = (double)s[t] / (double)N_NODESC;
        const double var = (double)s[64 + t] / (double)N_NODESC - mu * mu;
        const double sc  = (double)g[t] / sqrt(var + (double)EPSF);
        scale[t] = (float)sc;
        shift[t] = (float)((double)be[t] - mu * sc);
    }
}

// ---------------- final projection (LN apply fused) ----------------
__global__ __launch_bounds__(256)
void k_out(const float* __restrict__ outb, const float* __restrict__ scale,
           const float* __restrict__ shift, const float* __restrict__ resW,
           const float* __restrict__ resb, float* __restrict__ out)
{
    const int n = blockIdx.x * 256 + threadIdx.x;
    if (n >= N_NODESC) return;
    float a0 = resb[0], a1 = resb[1];
    const float* __restrict__ r = outb + (long)n * 64;
#pragma unroll 8
    for (int e = 0; e < 64; ++e) {
        const float v = fmaxf(r[e] * scale[e] + shift[e], 0.f);
        a0 += v * resW[2 * e];
        a1 += v * resW[2 * e + 1];
    }
    out[2 * n] = a0;
    out[2 * n + 1] = a1;
}

extern "C" void kernel_launch(void* const* d_in, const int* in_sizes, int n_in,
                              void* d_out, int out_size, void* d_ws, size_t ws_size,
                              hipStream_t stream)
{
    const float* x      = (const float*)d_in[0];
    const float* M      = (const float*)d_in[1];
    const int*   src    = (const int*)d_in[2];
    const int*   dst    = (const int*)d_in[3];
    const int*   labels = (const int*)d_in[4];
    const int*   bidx   = (const int*)d_in[5];
    const float* resW   = (const float*)d_in[18];
    const float* resb   = (const float*)d_in[19];
    float* out = (float*)d_out;

    char* ws = (char*)d_ws;
    float*  scale = (float*)(ws + WS_SCALE);
    float*  shift = (float*)(ws + WS_SHIFT);
    int*    bsum  = (int*)(ws + WS_BSUM);
    float*  pbuf  = (float*)(ws + WS_PBUF);
    int*    hist  = (int*)(ws + WS_HIST);
    int*    fill  = (int*)(ws + WS_FILL);
    int*    seg   = (int*)(ws + WS_SEG);
    int*    elist = (int*)(ws + WS_ELIST);
    ushort* Ahi   = (ushort*)(ws + WS_AHI);
    ushort* Alo   = (ushort*)(ws + WS_ALO);
    ushort* hhi   = (ushort*)(ws + WS_HHI);
    ushort* hlo   = (ushort*)(ws + WS_HLO);
    float*  hB    = (float*)(ws + WS_HB);
    float*  outb  = (float*)(ws + WS_OUTB);
    float*  pacc  = (float*)(ws + WS_PACC);

    const int NB64 = (N_NODESC * 64 + 255) / 256;  // 12500

    // ---- preprocessing (graph + M constant across layers) ----
    hipMemsetAsync(hist, 0, 2 * (size_t)NKEYS * sizeof(int), stream);  // hist + fill
    k_hist<<<NEBLK, 256, 0, stream>>>(src, dst, labels, bidx, hist);
    k_bsum<<<NHBLK, 256, 0, stream>>>(hist, bsum);
    k_bscan2<<<1, 1024, 0, stream>>>(bsum);
    k_escan2<<<NHBLK, 256, 0, stream>>>(hist, bsum, seg);
    k_scat<<<NEBLK, 256, 0, stream>>>(src, dst, labels, bidx, seg, fill, elist);
    k_mfrag<<<16, 256, 0, stream>>>(M, Ahi, Alo);

    for (int l = 0; l < 3; ++l) {
        const float* W  = (const float*)d_in[6 + 4 * l];
        const float* b  = (const float*)d_in[7 + 4 * l];
        const float* g  = (const float*)d_in[8 + 4 * l];
        const float* be = (const float*)d_in[9 + 4 * l];

        if (l == 0) {
            k_h<<<NB64, 256, 0, stream>>>(x, W, b, hB, hhi, hlo, 128);
        } else {
            k_happly<<<N_NODESC / 4, 256, 0, stream>>>(outb, scale, shift, W, b,
                                                       hB, hhi, hlo);
        }
        k_msgF<<<NQRT * SPLIT, 64, 0, stream>>>(hhi, hlo, elist, seg, Ahi, Alo, pacc);
        k_comb<<<NTILE, 256, 0, stream>>>(pacc, hB, outb, pbuf);
        k_norm2<<<1, 1024, 0, stream>>>(pbuf, g, be, scale, shift);
    }
    k_out<<<(N_NODESC + 255) / 256, 256, 0, stream>>>(outb, scale, shift, resW, resb, out);
    (void)in_sizes; (void)n_in; (void)out_size; (void)ws_size;
}